// Round 9
// baseline (451.296 us; speedup 1.0000x reference)
//
#include <hip/hip_runtime.h>
#include <math.h>

#define N_NODES 50000
#define N_EDGES 800000
#define IN_DIM 128
#define ED_DIM 32
#define NH 4
#define CH 16
#define HC 64
#define XS 68          // XW row stride: 64 xw + 4 als interleaved
#define NG 64
#define NCL 2
#define NEG_SLOPE 0.2f
#define LN_EPS 1e-5f
#define NBLK1 196   // ceil(50000/256)
#define NB_TILE 3125  // 50000/16 xw tiles == 800000/256 edge chunks
#define NB_ECH 3125   // 800000/256 edge chunks
#define AGG_BLOCKS 2048
#define AGG_WAVES (AGG_BLOCKS * 4)

// ---------- scan phase 1: per-block exclusive scan of cnt ----------
__global__ void k_scan_local(const int* __restrict__ cnt, int* __restrict__ tmp_ex,
                             int* __restrict__ bsum) {
    __shared__ int sd[256];
    int t = threadIdx.x, idx = blockIdx.x * 256 + t;
    int v = (idx < N_NODES) ? cnt[idx] : 0;
    sd[t] = v; __syncthreads();
    for (int off = 1; off < 256; off <<= 1) {
        int add = (t >= off) ? sd[t - off] : 0;
        __syncthreads();
        sd[t] += add;
        __syncthreads();
    }
    if (idx < N_NODES) tmp_ex[idx] = sd[t] - v;
    if (t == 255) bsum[blockIdx.x] = sd[t];
}

// ---------- fused phase 1: {xw1 | edge projection | degree hist} by blockIdx%3 ----------
// R2-proven form (84-88us): full W in LDS, 40KB, 4 blocks/CU. R3 (global-W) and
// R7 (chunked-W) both regressed — phase1 is not occupancy-bound; this is final.
__global__ __launch_bounds__(256) void k_phase1(
        const float* __restrict__ X, const float* __restrict__ W,
        const float* __restrict__ AS, const float* __restrict__ AD,
        float* __restrict__ XWA, float* __restrict__ ALD,
        const float* __restrict__ ea,
        const float* __restrict__ We1, const float* __restrict__ ae1,
        const float* __restrict__ We2, const float* __restrict__ ae2,
        float4* __restrict__ ale8,
        const int* __restrict__ dst, int* __restrict__ cnt, int* __restrict__ rank_e) {
    __shared__ float smem[IN_DIM * HC + 16 * IN_DIM];   // 40 KB, reused by all jobs
    int job = blockIdx.x % 3;
    int bid = blockIdx.x / 3;
    int t = threadIdx.x;
    if (job == 0) {
        const int K = IN_DIM;
        float* sW = smem;
        float* sX = smem + K * HC;
        for (int i = t; i < K * HC; i += 256) sW[i] = W[i];
        int nb = bid * 16;
        for (int i = t; i < 16 * K; i += 256) sX[i] = X[(long long)nb * K + i];
        __syncthreads();
        int sub = t >> 6, j = t & 63;
        float acc[4] = {0.f, 0.f, 0.f, 0.f};
        #pragma unroll 8
        for (int k = 0; k < K; ++k) {
            float wv = sW[k * HC + j];
            #pragma unroll
            for (int q = 0; q < 4; ++q) acc[q] += sX[(sub + 4 * q) * K + k] * wv;
        }
        float as_ = AS[j], ad_ = AD[j];
        #pragma unroll
        for (int q = 0; q < 4; ++q) {
            int n = nb + sub + 4 * q;
            XWA[(long long)n * XS + j] = acc[q];
            float vs = acc[q] * as_, vd = acc[q] * ad_;
            #pragma unroll
            for (int m = 1; m < 16; m <<= 1) { vs += __shfl_xor(vs, m); vd += __shfl_xor(vd, m); }
            if ((j & 15) == 0) {
                int h = j >> 4;
                XWA[(long long)n * XS + 64 + h] = vs;   // als interleaved with xw row
                ALD[n * 4 + h] = vd;
            }
        }
    } else if (job == 1) {
        float* sVe = smem;
        {
            int d = t >> 3, k = t & 7;
            int l = k >> 2, h = k & 3;
            const float* We = l ? We2 : We1;
            const float* ae = l ? ae2 : ae1;
            float s = 0.f;
            #pragma unroll
            for (int c = 0; c < CH; ++c) s += We[d * HC + h * CH + c] * ae[h * CH + c];
            sVe[d * 8 + k] = s;
        }
        __syncthreads();
        int e = bid * 256 + t;
        if (e >= N_EDGES) return;
        float a[8];
        #pragma unroll
        for (int k = 0; k < 8; ++k) a[k] = 0.f;
        const float4* er4 = (const float4*)(ea + (long long)e * ED_DIM);
        #pragma unroll
        for (int q = 0; q < ED_DIM / 4; ++q) {
            float4 v = er4[q];
            float ev[4] = {v.x, v.y, v.z, v.w};
            #pragma unroll
            for (int u = 0; u < 4; ++u) {
                #pragma unroll
                for (int k = 0; k < 8; ++k) a[k] += ev[u] * sVe[(q * 4 + u) * 8 + k];
            }
        }
        float4* out = ale8 + (long long)e * 2;
        out[0] = make_float4(a[0], a[1], a[2], a[3]);
        out[1] = make_float4(a[4], a[5], a[6], a[7]);
    } else {
        int e = bid * 256 + t;
        if (e < N_EDGES) rank_e[e] = atomicAdd(&cnt[dst[e]], 1);
    }
}

// ---------- fused: row_start finalize + perm scatter ----------
__global__ void k_scan_perm(const int* __restrict__ tmp_ex, const int* __restrict__ bsum,
                            int* __restrict__ row_start,
                            const int* __restrict__ dst, const int* __restrict__ srcI,
                            const int* __restrict__ rank_e, int2* __restrict__ perm_src) {
    __shared__ int sd[256];
    __shared__ int sboff[256];
    int t = threadIdx.x;
    int v = (t < NBLK1) ? bsum[t] : 0;
    sd[t] = v; __syncthreads();
    for (int off = 1; off < 256; off <<= 1) {
        int add = (t >= off) ? sd[t - off] : 0;
        __syncthreads();
        sd[t] += add;
        __syncthreads();
    }
    sboff[t] = sd[t] - v;   // exclusive prefix of bsum
    __syncthreads();
    if (blockIdx.x < NBLK1) {
        int idx = blockIdx.x * 256 + t;
        if (idx < N_NODES) row_start[idx] = tmp_ex[idx] + sboff[blockIdx.x];
        if (idx == 0) row_start[N_NODES] = N_EDGES;
    } else {
        int e = (blockIdx.x - NBLK1) * 256 + t;
        if (e < N_EDGES) {
            int d = dst[e];
            int pos = tmp_ex[d] + sboff[d >> 8] + rank_e[e];
            perm_src[pos] = make_int2(e, srcI[e]);
        }
    }
}

// ---------- xw = X @ W  (+ fused per-head al_src / al_dst), 16 nodes/block ----------
template<int K>
__global__ void k_xw(const float* __restrict__ X, const float* __restrict__ W,
                     const float* __restrict__ AS, const float* __restrict__ AD,
                     float* __restrict__ XWA, float* __restrict__ ALD) {
    __shared__ float sW[K * HC];
    __shared__ float sX[16 * K];
    int t = threadIdx.x;
    for (int i = t; i < K * HC; i += 256) sW[i] = W[i];
    int nb = blockIdx.x * 16;
    for (int i = t; i < 16 * K; i += 256) sX[i] = X[(long long)nb * K + i];
    __syncthreads();
    int sub = t >> 6, j = t & 63;
    float acc[4] = {0.f, 0.f, 0.f, 0.f};
    #pragma unroll 8
    for (int k = 0; k < K; ++k) {
        float wv = sW[k * HC + j];
        #pragma unroll
        for (int q = 0; q < 4; ++q) acc[q] += sX[(sub + 4 * q) * K + k] * wv;
    }
    float as_ = AS[j], ad_ = AD[j];
    #pragma unroll
    for (int q = 0; q < 4; ++q) {
        int n = nb + sub + 4 * q;
        XWA[(long long)n * XS + j] = acc[q];
        float vs = acc[q] * as_, vd = acc[q] * ad_;
        #pragma unroll
        for (int m = 1; m < 16; m <<= 1) { vs += __shfl_xor(vs, m); vd += __shfl_xor(vd, m); }
        if ((j & 15) == 0) {
            int h = j >> 4;
            XWA[(long long)n * XS + 64 + h] = vs;
            ALD[n * 4 + h] = vd;
        }
    }
}

// ---------- wave-per-node softmax aggregation, GRID-STRIDE waves ----------
// Per-node math identical to R2 (bit-exact). Grid-stride removes the tail drain
// of 12500 exit-early blocks; als is read from the gathered XW row (stride 68).
template<bool DO_LN, int LOFF>
__global__ void k_agg(const int* __restrict__ rs, const int2* __restrict__ ps,
                      const float* __restrict__ ale8,
                      const float* __restrict__ XWA, const float* __restrict__ ALD,
                      const float* __restrict__ bias,
                      const float* __restrict__ gam, const float* __restrict__ bet,
                      float* __restrict__ OUT) {
    int gw = (blockIdx.x * blockDim.x + threadIdx.x) >> 6;
    int lane = threadIdx.x & 63;
    int h = lane >> 4;
    for (int n = gw; n < N_NODES; n += AGG_WAVES) {
        int e0 = rs[n], e1 = rs[n + 1];
        float adn = ALD[n * 4 + h];
        float acc0 = 0.f, l0 = 0.f, as0 = 0.f;
        float acc1 = 0.f, l1 = 0.f, as1 = 0.f;
        float acc2 = 0.f, l2 = 0.f, as2 = 0.f;
        float acc3 = 0.f, l3 = 0.f, as3 = 0.f;
        int e = e0;
        for (; e + 3 < e1; e += 4) {
            int2 pA = ps[e], pB = ps[e + 1], pC = ps[e + 2], pD = ps[e + 3];
            float aeA = ale8[(long long)pA.x * 8 + LOFF + h];
            float aeB = ale8[(long long)pB.x * 8 + LOFF + h];
            float aeC = ale8[(long long)pC.x * 8 + LOFF + h];
            float aeD = ale8[(long long)pD.x * 8 + LOFF + h];
            float xA = XWA[(long long)pA.y * XS + lane];
            float xB = XWA[(long long)pB.y * XS + lane];
            float xC = XWA[(long long)pC.y * XS + lane];
            float xD = XWA[(long long)pD.y * XS + lane];
            float aA = XWA[(long long)pA.y * XS + 64 + h] + adn + aeA;
            float aB = XWA[(long long)pB.y * XS + 64 + h] + adn + aeB;
            float aC = XWA[(long long)pC.y * XS + 64 + h] + adn + aeC;
            float aD = XWA[(long long)pD.y * XS + 64 + h] + adn + aeD;
            aA = aA > 0.f ? aA : NEG_SLOPE * aA;
            aB = aB > 0.f ? aB : NEG_SLOPE * aB;
            aC = aC > 0.f ? aC : NEG_SLOPE * aC;
            aD = aD > 0.f ? aD : NEG_SLOPE * aD;
            float qA = __expf(aA), qB = __expf(aB), qC = __expf(aC), qD = __expf(aD);
            acc0 += qA * xA; l0 += qA; as0 += aeA;
            acc1 += qB * xB; l1 += qB; as1 += aeB;
            acc2 += qC * xC; l2 += qC; as2 += aeC;
            acc3 += qD * xD; l3 += qD; as3 += aeD;
        }
        for (; e < e1; ++e) {
            int2 pA = ps[e];
            float aeA = ale8[(long long)pA.x * 8 + LOFF + h];
            float xA = XWA[(long long)pA.y * XS + lane];
            float aA = XWA[(long long)pA.y * XS + 64 + h] + adn + aeA;
            aA = aA > 0.f ? aA : NEG_SLOPE * aA;
            float qA = __expf(aA);
            acc0 += qA * xA; l0 += qA; as0 += aeA;
        }
        // self loop: ale_self = mean of row's ale (linearity of edge projection)
        int d = e1 - e0;
        float invd = 1.f / (float)(d > 0 ? d : 1);
        float aSelf = XWA[(long long)n * XS + 64 + h] + adn + (as0 + as1 + as2 + as3) * invd;
        aSelf = aSelf > 0.f ? aSelf : NEG_SLOPE * aSelf;
        float pS = __expf(aSelf);
        float acc = (acc0 + acc1) + (acc2 + acc3) + pS * XWA[(long long)n * XS + lane];
        float l = (l0 + l1) + (l2 + l3) + pS;
        float v = acc / (l + 1e-16f) + bias[lane];
        v = fmaxf(v, 0.f);
        if (DO_LN) {
            float s1 = v;
            #pragma unroll
            for (int mm = 1; mm < 64; mm <<= 1) s1 += __shfl_xor(s1, mm);
            float mean = s1 * (1.f / 64.f);
            float dd = v - mean;
            float s2 = dd * dd;
            #pragma unroll
            for (int mm = 1; mm < 64; mm <<= 1) s2 += __shfl_xor(s2, mm);
            float var = s2 * (1.f / 64.f);
            v = dd * rsqrtf(var + LN_EPS) * gam[lane] + bet[lane];
        }
        OUT[(long long)n * HC + lane] = v;
    }
}

// ---------- global max pool by (sorted) batch; values >= 0 ----------
__global__ void k_pool(const float* __restrict__ H2, const int* __restrict__ batch,
                       float* __restrict__ pooled) {
    int j = threadIdx.x & 63;
    int r = threadIdx.x >> 6;          // 4 rows in parallel
    int base = blockIdx.x * 128;
    int gcur = -1; float rm = 0.f;
    for (int n = base + r; n < base + 128 && n < N_NODES; n += 4) {
        int g = batch[n];
        if (g != gcur) {
            if (gcur >= 0) atomicMax((unsigned int*)&pooled[gcur * HC + j], __float_as_uint(rm));
            gcur = g; rm = 0.f;
        }
        rm = fmaxf(rm, H2[(long long)n * HC + j]);
    }
    if (gcur >= 0) atomicMax((unsigned int*)&pooled[gcur * HC + j], __float_as_uint(rm));
}

// ---------- head: fc1 + LN + relu + fc2 + log_softmax ----------
__global__ void k_head(const float* __restrict__ pooled,
                       const float* __restrict__ fw1, const float* __restrict__ fb1,
                       const float* __restrict__ g2, const float* __restrict__ be2,
                       const float* __restrict__ fw2, const float* __restrict__ fb2,
                       float* __restrict__ out) {
    int g = blockIdx.x;
    int j = threadIdx.x;                // 64 threads, lanes 0..31 active for math
    float z = 0.f;
    if (j < 32) {
        for (int k = 0; k < HC; ++k) z += pooled[g * HC + k] * fw1[k * 32 + j];
        z += fb1[j];
    }
    float s1 = (j < 32) ? z : 0.f;
    for (int m = 1; m < 32; m <<= 1) s1 += __shfl_xor(s1, m, 32);
    float mean = s1 * (1.f / 32.f);
    float d = z - mean;
    float s2 = (j < 32) ? d * d : 0.f;
    for (int m = 1; m < 32; m <<= 1) s2 += __shfl_xor(s2, m, 32);
    float var = s2 * (1.f / 32.f);
    float zz = 0.f;
    if (j < 32) {
        zz = d * rsqrtf(var + LN_EPS) * g2[j] + be2[j];
        zz = fmaxf(zz, 0.f);
    }
    float p0 = (j < 32) ? zz * fw2[j * NCL + 0] : 0.f;
    float p1 = (j < 32) ? zz * fw2[j * NCL + 1] : 0.f;
    for (int m = 1; m < 32; m <<= 1) { p0 += __shfl_xor(p0, m, 32); p1 += __shfl_xor(p1, m, 32); }
    if (j == 0) {
        float l0 = p0 + fb2[0], l1 = p1 + fb2[1];
        float mx = fmaxf(l0, l1);
        float ls = mx + logf(__expf(l0 - mx) + __expf(l1 - mx));
        out[g * NCL + 0] = l0 - ls;
        out[g * NCL + 1] = l1 - ls;
    }
}

extern "C" void kernel_launch(void* const* d_in, const int* in_sizes, int n_in,
                              void* d_out, int out_size, void* d_ws, size_t ws_size,
                              hipStream_t stream) {
    const float* x   = (const float*)d_in[0];
    const float* ea  = (const float*)d_in[1];
    const float* W1  = (const float*)d_in[2];
    const float* as1 = (const float*)d_in[3];
    const float* ad1 = (const float*)d_in[4];
    const float* We1 = (const float*)d_in[5];
    const float* ae1 = (const float*)d_in[6];
    const float* b1  = (const float*)d_in[7];
    const float* W2  = (const float*)d_in[8];
    const float* as2 = (const float*)d_in[9];
    const float* ad2 = (const float*)d_in[10];
    const float* We2 = (const float*)d_in[11];
    const float* ae2 = (const float*)d_in[12];
    const float* b2  = (const float*)d_in[13];
    const float* g1  = (const float*)d_in[14];
    const float* be1 = (const float*)d_in[15];
    const float* fw1 = (const float*)d_in[16];
    const float* fb1 = (const float*)d_in[17];
    const float* g2  = (const float*)d_in[18];
    const float* be2 = (const float*)d_in[19];
    const float* fw2 = (const float*)d_in[20];
    const float* fb2 = (const float*)d_in[21];
    const int* eidx  = (const int*)d_in[22];
    const int* batch = (const int*)d_in[23];
    const int* srcI = eidx;
    const int* dstI = eidx + N_EDGES;

    char* w = (char*)d_ws;
    auto alloc = [&](size_t bytes) { char* p = w; w += (bytes + 255) & ~(size_t)255; return p; };
    int*   cnt       = (int*)  alloc((size_t)N_NODES * 4);
    int*   row_start = (int*)  alloc((size_t)(N_NODES + 1) * 4);
    int*   rank_e    = (int*)  alloc((size_t)N_EDGES * 4);
    int*   tmp_ex    = (int*)  alloc((size_t)N_NODES * 4);
    int*   bsum      = (int*)  alloc(256 * 4);
    int2*  perm_src  = (int2*) alloc((size_t)N_EDGES * 8);
    float4* ale8     = (float4*)alloc((size_t)N_EDGES * 32);
    float* xwa1      = (float*)alloc((size_t)N_NODES * XS * 4);   // reused as xwa2
    float* ald1      = (float*)alloc((size_t)N_NODES * 4 * 4);
    float* h1        = (float*)alloc((size_t)N_NODES * HC * 4);   // reused as h2
    float* ald2      = (float*)alloc((size_t)N_NODES * 4 * 4);
    float* pooled    = (float*)alloc((size_t)NG * HC * 4);
    float* xwa2 = xwa1;   // lifetime of xwa1 ends at k_agg<true>
    float* h2  = h1;      // lifetime of h1 ends at k_xw<HC>

    hipMemsetAsync(cnt, 0, (size_t)N_NODES * 4, stream);
    hipMemsetAsync(pooled, 0, (size_t)NG * HC * 4, stream);

    // Phase 1: xw1 | edge projection | degree hist — independent, one dispatch
    k_phase1<<<3 * NB_TILE, 256, 0, stream>>>(x, W1, as1, ad1, xwa1, ald1,
                                              ea, We1, ae1, We2, ae2, ale8,
                                              dstI, cnt, rank_e);
    k_scan_local<<<NBLK1, 256, 0, stream>>>(cnt, tmp_ex, bsum);
    // row_start finalize + perm scatter in one dispatch
    k_scan_perm<<<NBLK1 + NB_ECH, 256, 0, stream>>>(tmp_ex, bsum, row_start,
                                                    dstI, srcI, rank_e, perm_src);

    // Layer 1 aggregate with fused bias/ReLU/LayerNorm (grid-stride)
    k_agg<true, 0><<<AGG_BLOCKS, 256, 0, stream>>>(row_start, perm_src, (const float*)ale8,
                                                   xwa1, ald1, b1, g1, be1, h1);
    // Layer 2: xw + aggregate (fused bias/ReLU only)
    k_xw<HC><<<NB_TILE, 256, 0, stream>>>(h1, W2, as2, ad2, xwa2, ald2);
    k_agg<false, 4><<<AGG_BLOCKS, 256, 0, stream>>>(row_start, perm_src, (const float*)ale8,
                                                    xwa2, ald2, b2, nullptr, nullptr, h2);

    k_pool<<<(N_NODES + 127) / 128, 256, 0, stream>>>(h2, batch, pooled);
    k_head<<<NG, 64, 0, stream>>>(pooled, fw1, fb1, g2, be2, fw2, fb2, (float*)d_out);
}

// Round 11
// 407.630 us; speedup vs baseline: 1.1071x; 1.1071x over previous
//
#include <hip/hip_runtime.h>
#include <math.h>

#define N_NODES 50000
#define N_EDGES 800000
#define IN_DIM 128
#define ED_DIM 32
#define NH 4
#define CH 16
#define HC 64
#define NG 64
#define NCL 2
#define NEG_SLOPE 0.2f
#define LN_EPS 1e-5f
#define NBLK1 196   // ceil(50000/256)
#define NB_TILE 3125  // 50000/16 xw tiles == 800000/256 edge chunks
#define NB_ECH 3125   // 800000/256 edge chunks

// ---------- scan phase 1: per-block exclusive scan of cnt ----------
__global__ void k_scan_local(const int* __restrict__ cnt, int* __restrict__ tmp_ex,
                             int* __restrict__ bsum) {
    __shared__ int sd[256];
    int t = threadIdx.x, idx = blockIdx.x * 256 + t;
    int v = (idx < N_NODES) ? cnt[idx] : 0;
    sd[t] = v; __syncthreads();
    for (int off = 1; off < 256; off <<= 1) {
        int add = (t >= off) ? sd[t - off] : 0;
        __syncthreads();
        sd[t] += add;
        __syncthreads();
    }
    if (idx < N_NODES) tmp_ex[idx] = sd[t] - v;
    if (t == 255) bsum[blockIdx.x] = sd[t];
}

// ---------- fused phase 1: {xw1 | edge projection | degree hist} by blockIdx%3 ----------
// Round-3-proven form (418.6us total). Single change vs round 3: job1 stages its
// 256 edge rows into LDS with COALESCED float4 loads (padded stride 33 words,
// bank-conflict-free) instead of per-thread 128B-stride reads, cutting the
// vmem transaction count of the ea stream ~4x. Per-edge FP order unchanged.
__global__ __launch_bounds__(256) void k_phase1(
        const float* __restrict__ X, const float* __restrict__ W,
        const float* __restrict__ AS, const float* __restrict__ AD,
        float* __restrict__ XW, float* __restrict__ ALS, float* __restrict__ ALD,
        const float* __restrict__ ea,
        const float* __restrict__ We1, const float* __restrict__ ae1,
        const float* __restrict__ We2, const float* __restrict__ ae2,
        float4* __restrict__ ale8,
        const int* __restrict__ dst, int* __restrict__ cnt, int* __restrict__ rank_e) {
    __shared__ float smem[IN_DIM * HC + 16 * IN_DIM];   // 40 KB, reused by all jobs
    int job = blockIdx.x % 3;
    int bid = blockIdx.x / 3;
    int t = threadIdx.x;
    if (job == 0) {
        const int K = IN_DIM;
        float* sW = smem;
        float* sX = smem + K * HC;
        for (int i = t; i < K * HC; i += 256) sW[i] = W[i];
        int nb = bid * 16;
        for (int i = t; i < 16 * K; i += 256) sX[i] = X[(long long)nb * K + i];
        __syncthreads();
        int sub = t >> 6, j = t & 63;
        float acc[4] = {0.f, 0.f, 0.f, 0.f};
        #pragma unroll 8
        for (int k = 0; k < K; ++k) {
            float wv = sW[k * HC + j];
            #pragma unroll
            for (int q = 0; q < 4; ++q) acc[q] += sX[(sub + 4 * q) * K + k] * wv;
        }
        float as_ = AS[j], ad_ = AD[j];
        #pragma unroll
        for (int q = 0; q < 4; ++q) {
            int n = nb + sub + 4 * q;
            XW[(long long)n * HC + j] = acc[q];
            float vs = acc[q] * as_, vd = acc[q] * ad_;
            #pragma unroll
            for (int m = 1; m < 16; m <<= 1) { vs += __shfl_xor(vs, m); vd += __shfl_xor(vd, m); }
            if ((j & 15) == 0) {
                int h = j >> 4;
                ALS[n * 4 + h] = vs; ALD[n * 4 + h] = vd;
            }
        }
    } else if (job == 1) {
        float* sVe = smem;              // 256 floats
        float* sE  = smem + 256;        // 256 edges x 33 words (padded) = 33.8 KB
        {
            int d = t >> 3, k = t & 7;
            int l = k >> 2, h = k & 3;
            const float* We = l ? We2 : We1;
            const float* ae = l ? ae2 : ae1;
            float s = 0.f;
            #pragma unroll
            for (int c = 0; c < CH; ++c) s += We[d * HC + h * CH + c] * ae[h * CH + c];
            sVe[d * 8 + k] = s;
        }
        // coalesced staging of this block's 256 edge rows (2048 float4s)
        {
            const float4* gsrc = (const float4*)ea + (size_t)bid * 2048;
            #pragma unroll
            for (int r = 0; r < 8; ++r) {
                int i4 = t + r * 256;
                float4 v = gsrc[i4];
                float* dp = sE + (i4 >> 3) * 33 + ((i4 & 7) << 2);
                dp[0] = v.x; dp[1] = v.y; dp[2] = v.z; dp[3] = v.w;
            }
        }
        __syncthreads();
        int e = bid * 256 + t;
        float a[8];
        #pragma unroll
        for (int k = 0; k < 8; ++k) a[k] = 0.f;
        const float* row = sE + t * 33;   // bank = (t+i)%32 -> 2 lanes/bank, free
        #pragma unroll
        for (int q = 0; q < ED_DIM / 4; ++q) {
            #pragma unroll
            for (int u = 0; u < 4; ++u) {
                float ev = row[q * 4 + u];
                #pragma unroll
                for (int k = 0; k < 8; ++k) a[k] += ev * sVe[(q * 4 + u) * 8 + k];
            }
        }
        float4* out = ale8 + (long long)e * 2;
        out[0] = make_float4(a[0], a[1], a[2], a[3]);
        out[1] = make_float4(a[4], a[5], a[6], a[7]);
    } else {
        int e = bid * 256 + t;
        if (e < N_EDGES) rank_e[e] = atomicAdd(&cnt[dst[e]], 1);
    }
}

// ---------- fused: row_start finalize + perm scatter ----------
__global__ void k_scan_perm(const int* __restrict__ tmp_ex, const int* __restrict__ bsum,
                            int* __restrict__ row_start,
                            const int* __restrict__ dst, const int* __restrict__ srcI,
                            const int* __restrict__ rank_e, int2* __restrict__ perm_src) {
    __shared__ int sd[256];
    __shared__ int sboff[256];
    int t = threadIdx.x;
    int v = (t < NBLK1) ? bsum[t] : 0;
    sd[t] = v; __syncthreads();
    for (int off = 1; off < 256; off <<= 1) {
        int add = (t >= off) ? sd[t - off] : 0;
        __syncthreads();
        sd[t] += add;
        __syncthreads();
    }
    sboff[t] = sd[t] - v;   // exclusive prefix of bsum
    __syncthreads();
    if (blockIdx.x < NBLK1) {
        int idx = blockIdx.x * 256 + t;
        if (idx < N_NODES) row_start[idx] = tmp_ex[idx] + sboff[blockIdx.x];
        if (idx == 0) row_start[N_NODES] = N_EDGES;
    } else {
        int e = (blockIdx.x - NBLK1) * 256 + t;
        if (e < N_EDGES) {
            int d = dst[e];
            int pos = tmp_ex[d] + sboff[d >> 8] + rank_e[e];
            perm_src[pos] = make_int2(e, srcI[e]);
        }
    }
}

// ---------- xw = X @ W  (+ fused per-head al_src / al_dst), 16 nodes/block ----------
template<int K>
__global__ void k_xw(const float* __restrict__ X, const float* __restrict__ W,
                     const float* __restrict__ AS, const float* __restrict__ AD,
                     float* __restrict__ XW, float* __restrict__ ALS, float* __restrict__ ALD) {
    __shared__ float sW[K * HC];
    __shared__ float sX[16 * K];
    int t = threadIdx.x;
    for (int i = t; i < K * HC; i += 256) sW[i] = W[i];
    int nb = blockIdx.x * 16;
    for (int i = t; i < 16 * K; i += 256) sX[i] = X[(long long)nb * K + i];
    __syncthreads();
    int sub = t >> 6, j = t & 63;
    float acc[4] = {0.f, 0.f, 0.f, 0.f};
    #pragma unroll 8
    for (int k = 0; k < K; ++k) {
        float wv = sW[k * HC + j];
        #pragma unroll
        for (int q = 0; q < 4; ++q) acc[q] += sX[(sub + 4 * q) * K + k] * wv;
    }
    float as_ = AS[j], ad_ = AD[j];
    #pragma unroll
    for (int q = 0; q < 4; ++q) {
        int n = nb + sub + 4 * q;
        XW[(long long)n * HC + j] = acc[q];
        float vs = acc[q] * as_, vd = acc[q] * ad_;
        #pragma unroll
        for (int m = 1; m < 16; m <<= 1) { vs += __shfl_xor(vs, m); vd += __shfl_xor(vd, m); }
        if ((j & 15) == 0) {
            int h = j >> 4;
            ALS[n * 4 + h] = vs; ALD[n * 4 + h] = vd;
        }
    }
}

// ---------- wave-per-node softmax aggregation (+self-loop, bias/ReLU[/LN]) ----------
// Round-3-proven form: 4-wide, aligned 64-float XW rows, separate ALS, early exit.
template<bool DO_LN, int LOFF>
__global__ void k_agg(const int* __restrict__ rs, const int2* __restrict__ ps,
                      const float* __restrict__ ale8,
                      const float* __restrict__ ALS, const float* __restrict__ ALD,
                      const float* __restrict__ XW, const float* __restrict__ bias,
                      const float* __restrict__ gam, const float* __restrict__ bet,
                      float* __restrict__ OUT) {
    int n = (blockIdx.x * blockDim.x + threadIdx.x) >> 6;
    if (n >= N_NODES) return;
    int lane = threadIdx.x & 63;
    int h = lane >> 4;
    int e0 = rs[n], e1 = rs[n + 1];
    float adn = ALD[n * 4 + h];
    float acc0 = 0.f, l0 = 0.f, as0 = 0.f;
    float acc1 = 0.f, l1 = 0.f, as1 = 0.f;
    float acc2 = 0.f, l2 = 0.f, as2 = 0.f;
    float acc3 = 0.f, l3 = 0.f, as3 = 0.f;
    int e = e0;
    for (; e + 3 < e1; e += 4) {
        int2 pA = ps[e], pB = ps[e + 1], pC = ps[e + 2], pD = ps[e + 3];
        float aeA = ale8[(long long)pA.x * 8 + LOFF + h];
        float aeB = ale8[(long long)pB.x * 8 + LOFF + h];
        float aeC = ale8[(long long)pC.x * 8 + LOFF + h];
        float aeD = ale8[(long long)pD.x * 8 + LOFF + h];
        float xA = XW[pA.y * HC + lane];
        float xB = XW[pB.y * HC + lane];
        float xC = XW[pC.y * HC + lane];
        float xD = XW[pD.y * HC + lane];
        float aA = ALS[pA.y * 4 + h] + adn + aeA;
        float aB = ALS[pB.y * 4 + h] + adn + aeB;
        float aC = ALS[pC.y * 4 + h] + adn + aeC;
        float aD = ALS[pD.y * 4 + h] + adn + aeD;
        aA = aA > 0.f ? aA : NEG_SLOPE * aA;
        aB = aB > 0.f ? aB : NEG_SLOPE * aB;
        aC = aC > 0.f ? aC : NEG_SLOPE * aC;
        aD = aD > 0.f ? aD : NEG_SLOPE * aD;
        float qA = __expf(aA), qB = __expf(aB), qC = __expf(aC), qD = __expf(aD);
        acc0 += qA * xA; l0 += qA; as0 += aeA;
        acc1 += qB * xB; l1 += qB; as1 += aeB;
        acc2 += qC * xC; l2 += qC; as2 += aeC;
        acc3 += qD * xD; l3 += qD; as3 += aeD;
    }
    for (; e < e1; ++e) {
        int2 pA = ps[e];
        float aeA = ale8[(long long)pA.x * 8 + LOFF + h];
        float xA = XW[pA.y * HC + lane];
        float aA = ALS[pA.y * 4 + h] + adn + aeA;
        aA = aA > 0.f ? aA : NEG_SLOPE * aA;
        float qA = __expf(aA);
        acc0 += qA * xA; l0 += qA; as0 += aeA;
    }
    // self loop: ale_self = mean of row's ale (linearity of edge projection)
    int d = e1 - e0;
    float invd = 1.f / (float)(d > 0 ? d : 1);
    float aSelf = ALS[n * 4 + h] + adn + (as0 + as1 + as2 + as3) * invd;
    aSelf = aSelf > 0.f ? aSelf : NEG_SLOPE * aSelf;
    float pS = __expf(aSelf);
    float acc = (acc0 + acc1) + (acc2 + acc3) + pS * XW[n * HC + lane];
    float l = (l0 + l1) + (l2 + l3) + pS;
    float v = acc / (l + 1e-16f) + bias[lane];
    v = fmaxf(v, 0.f);
    if (DO_LN) {
        float s1 = v;
        #pragma unroll
        for (int mm = 1; mm < 64; mm <<= 1) s1 += __shfl_xor(s1, mm);
        float mean = s1 * (1.f / 64.f);
        float dd = v - mean;
        float s2 = dd * dd;
        #pragma unroll
        for (int mm = 1; mm < 64; mm <<= 1) s2 += __shfl_xor(s2, mm);
        float var = s2 * (1.f / 64.f);
        v = dd * rsqrtf(var + LN_EPS) * gam[lane] + bet[lane];
    }
    OUT[(long long)n * HC + lane] = v;
}

// ---------- global max pool by (sorted) batch; values >= 0 ----------
__global__ void k_pool(const float* __restrict__ H2, const int* __restrict__ batch,
                       float* __restrict__ pooled) {
    int j = threadIdx.x & 63;
    int r = threadIdx.x >> 6;          // 4 rows in parallel
    int base = blockIdx.x * 128;
    int gcur = -1; float rm = 0.f;
    for (int n = base + r; n < base + 128 && n < N_NODES; n += 4) {
        int g = batch[n];
        if (g != gcur) {
            if (gcur >= 0) atomicMax((unsigned int*)&pooled[gcur * HC + j], __float_as_uint(rm));
            gcur = g; rm = 0.f;
        }
        rm = fmaxf(rm, H2[(long long)n * HC + j]);
    }
    if (gcur >= 0) atomicMax((unsigned int*)&pooled[gcur * HC + j], __float_as_uint(rm));
}

// ---------- head: fc1 + LN + relu + fc2 + log_softmax ----------
__global__ void k_head(const float* __restrict__ pooled,
                       const float* __restrict__ fw1, const float* __restrict__ fb1,
                       const float* __restrict__ g2, const float* __restrict__ be2,
                       const float* __restrict__ fw2, const float* __restrict__ fb2,
                       float* __restrict__ out) {
    int g = blockIdx.x;
    int j = threadIdx.x;                // 64 threads, lanes 0..31 active for math
    float z = 0.f;
    if (j < 32) {
        for (int k = 0; k < HC; ++k) z += pooled[g * HC + k] * fw1[k * 32 + j];
        z += fb1[j];
    }
    float s1 = (j < 32) ? z : 0.f;
    for (int m = 1; m < 32; m <<= 1) s1 += __shfl_xor(s1, m, 32);
    float mean = s1 * (1.f / 32.f);
    float d = z - mean;
    float s2 = (j < 32) ? d * d : 0.f;
    for (int m = 1; m < 32; m <<= 1) s2 += __shfl_xor(s2, m, 32);
    float var = s2 * (1.f / 32.f);
    float zz = 0.f;
    if (j < 32) {
        zz = d * rsqrtf(var + LN_EPS) * g2[j] + be2[j];
        zz = fmaxf(zz, 0.f);
    }
    float p0 = (j < 32) ? zz * fw2[j * NCL + 0] : 0.f;
    float p1 = (j < 32) ? zz * fw2[j * NCL + 1] : 0.f;
    for (int m = 1; m < 32; m <<= 1) { p0 += __shfl_xor(p0, m, 32); p1 += __shfl_xor(p1, m, 32); }
    if (j == 0) {
        float l0 = p0 + fb2[0], l1 = p1 + fb2[1];
        float mx = fmaxf(l0, l1);
        float ls = mx + logf(__expf(l0 - mx) + __expf(l1 - mx));
        out[g * NCL + 0] = l0 - ls;
        out[g * NCL + 1] = l1 - ls;
    }
}

extern "C" void kernel_launch(void* const* d_in, const int* in_sizes, int n_in,
                              void* d_out, int out_size, void* d_ws, size_t ws_size,
                              hipStream_t stream) {
    const float* x   = (const float*)d_in[0];
    const float* ea  = (const float*)d_in[1];
    const float* W1  = (const float*)d_in[2];
    const float* as1 = (const float*)d_in[3];
    const float* ad1 = (const float*)d_in[4];
    const float* We1 = (const float*)d_in[5];
    const float* ae1 = (const float*)d_in[6];
    const float* b1  = (const float*)d_in[7];
    const float* W2  = (const float*)d_in[8];
    const float* as2 = (const float*)d_in[9];
    const float* ad2 = (const float*)d_in[10];
    const float* We2 = (const float*)d_in[11];
    const float* ae2 = (const float*)d_in[12];
    const float* b2  = (const float*)d_in[13];
    const float* g1  = (const float*)d_in[14];
    const float* be1 = (const float*)d_in[15];
    const float* fw1 = (const float*)d_in[16];
    const float* fb1 = (const float*)d_in[17];
    const float* g2  = (const float*)d_in[18];
    const float* be2 = (const float*)d_in[19];
    const float* fw2 = (const float*)d_in[20];
    const float* fb2 = (const float*)d_in[21];
    const int* eidx  = (const int*)d_in[22];
    const int* batch = (const int*)d_in[23];
    const int* srcI = eidx;
    const int* dstI = eidx + N_EDGES;

    char* w = (char*)d_ws;
    auto alloc = [&](size_t bytes) { char* p = w; w += (bytes + 255) & ~(size_t)255; return p; };
    int*   cnt       = (int*)  alloc((size_t)N_NODES * 4);
    int*   row_start = (int*)  alloc((size_t)(N_NODES + 1) * 4);
    int*   rank_e    = (int*)  alloc((size_t)N_EDGES * 4);
    int*   tmp_ex    = (int*)  alloc((size_t)N_NODES * 4);
    int*   bsum      = (int*)  alloc(256 * 4);
    int2*  perm_src  = (int2*) alloc((size_t)N_EDGES * 8);
    float4* ale8     = (float4*)alloc((size_t)N_EDGES * 32);
    float* xw1       = (float*)alloc((size_t)N_NODES * HC * 4);   // reused as xw2
    float* als1      = (float*)alloc((size_t)N_NODES * 4 * 4);
    float* ald1      = (float*)alloc((size_t)N_NODES * 4 * 4);
    float* h1        = (float*)alloc((size_t)N_NODES * HC * 4);   // reused as h2
    float* als2      = (float*)alloc((size_t)N_NODES * 4 * 4);
    float* ald2      = (float*)alloc((size_t)N_NODES * 4 * 4);
    float* pooled    = (float*)alloc((size_t)NG * HC * 4);
    float* xw2 = xw1;   // lifetime of xw1 ends at k_agg<true>
    float* h2  = h1;    // lifetime of h1 ends at k_xw<HC>

    hipMemsetAsync(cnt, 0, (size_t)N_NODES * 4, stream);
    hipMemsetAsync(pooled, 0, (size_t)NG * HC * 4, stream);

    // Phase 1: xw1 | edge projection | degree hist — independent, one dispatch
    k_phase1<<<3 * NB_TILE, 256, 0, stream>>>(x, W1, as1, ad1, xw1, als1, ald1,
                                              ea, We1, ae1, We2, ae2, ale8,
                                              dstI, cnt, rank_e);
    k_scan_local<<<NBLK1, 256, 0, stream>>>(cnt, tmp_ex, bsum);
    // row_start finalize + perm scatter in one dispatch
    k_scan_perm<<<NBLK1 + NB_ECH, 256, 0, stream>>>(tmp_ex, bsum, row_start,
                                                    dstI, srcI, rank_e, perm_src);

    // Layer 1 aggregate with fused bias/ReLU/LayerNorm
    k_agg<true, 0><<<N_NODES / 4, 256, 0, stream>>>(row_start, perm_src, (const float*)ale8,
                                                    als1, ald1, xw1, b1, g1, be1, h1);
    // Layer 2: xw + aggregate (fused bias/ReLU only)
    k_xw<HC><<<NB_TILE, 256, 0, stream>>>(h1, W2, as2, ad2, xw2, als2, ald2);
    k_agg<false, 4><<<N_NODES / 4, 256, 0, stream>>>(row_start, perm_src, (const float*)ale8,
                                                     als2, ald2, xw2, b2, nullptr, nullptr, h2);

    k_pool<<<(N_NODES + 127) / 128, 256, 0, stream>>>(h2, batch, pooled);
    k_head<<<NG, 64, 0, stream>>>(pooled, fw1, fb1, g2, be2, fw2, fb2, (float*)d_out);
}